// Round 6
// baseline (345.623 us; speedup 1.0000x reference)
//
#include <hip/hip_runtime.h>
#include <math.h>

#define B_  32
#define L_  2048
#define D_  64      // padded head dim (50 -> 64)
#define SR  66      // stage row stride in u16 (33 dwords, odd -> distinct bank starts)
#define PR  34      // P row stride in u16 (17 dwords)
#define LOG2E 1.44269504088896340736f

typedef unsigned short u16;
typedef float f32x4  __attribute__((ext_vector_type(4)));
typedef float f32x16 __attribute__((ext_vector_type(16)));
typedef short s16x8  __attribute__((ext_vector_type(8)));
typedef unsigned short u16x4v __attribute__((ext_vector_type(4)));

__device__ inline float scalar_as_float(const int* p) {
    int v = *p;
    return (v > 0 && v < (1 << 23)) ? (float)v : __int_as_float(v);
}
__device__ inline float fexp2(float x) {
#if __has_builtin(__builtin_amdgcn_exp2f)
    return __builtin_amdgcn_exp2f(x);
#else
    return exp2f(x);
#endif
}
__device__ inline float frcp(float x) {
#if __has_builtin(__builtin_amdgcn_rcpf)
    return __builtin_amdgcn_rcpf(x);
#else
    return 1.0f / x;
#endif
}
__device__ inline float fast_elu(float a) {
    return a > 0.f ? a : fexp2(a * LOG2E) - 1.0f;
}
__device__ inline float fast_tanh(float a) {
    a = fminf(fmaxf(a, -20.f), 20.f);
    const float t = fexp2(a * (2.0f * LOG2E));
    return (t - 1.0f) * frcp(t + 1.0f);
}
__device__ inline u16 f2bf_rne(float f) {
    unsigned int u = __float_as_uint(f);
    u += 0x7fffu + ((u >> 16) & 1u);
    return (u16)(u >> 16);
}
__device__ inline void bfsplit(float x, u16& h, u16& l) {
    unsigned int u = __float_as_uint(x);
    h = (u16)(u >> 16);
    l = f2bf_rne(x - __uint_as_float(u & 0xffff0000u));
}
__device__ inline f32x16 mfma32(s16x8 a, s16x8 b, f32x16 c) {
    return __builtin_amdgcn_mfma_f32_32x32x16_bf16(a, b, c, 0, 0, 0);
}

// -------------------- Kernel 1: projections -> bf16 (unchanged) ------------
__device__ inline void matvec16(const float (*xs)[64], const float* ws,
                                const float* bsh, int r, int sg, float* acc)
{
    #pragma unroll
    for (int jj = 0; jj < 16; ++jj) acc[jj] = bsh[sg * 16 + jj];
    #pragma unroll 4
    for (int c = 0; c < 64; ++c) {
        const float xv = xs[c][r];
        const f32x4* wr = (const f32x4*)(ws + c * 64 + sg * 16);
        #pragma unroll
        for (int q = 0; q < 4; ++q) {
            const f32x4 w = wr[q];
            #pragma unroll
            for (int i = 0; i < 4; ++i)
                acc[q * 4 + i] = fmaf(xv, w[i], acc[q * 4 + i]);
        }
    }
}

__global__ __launch_bounds__(256)
void kqv_kernel(const float* __restrict__ x,
                const float* __restrict__ Wk, const float* __restrict__ bk,
                const float* __restrict__ Wq, const float* __restrict__ bq,
                const float* __restrict__ Wv, const float* __restrict__ bv,
                const int* __restrict__ slen,
                u16* __restrict__ Khi, u16* __restrict__ Klo,
                u16* __restrict__ Qhi, u16* __restrict__ Qlo,
                u16* __restrict__ Vthi)
{
    __shared__ __align__(16) float xs[64][64];
    __shared__ __align__(16) float ws[64 * 64];
    __shared__ __align__(16) float vt[64 * 68];
    __shared__ __align__(16) float bsh[64];

    const int t  = threadIdx.x;
    const int b  = blockIdx.y;
    const int l0 = blockIdx.x * 64;
    const int li = t & 63;
    const int g  = t >> 6;
    const int r  = t >> 2;
    const int sg = t & 3;

    for (int c = g; c < 64; c += 4)
        xs[c][li] = x[((size_t)b * 64 + c) * L_ + l0 + li];

    const float sc2 = rsqrtf(scalar_as_float(slen)) * LOG2E;
    float acc[16];

    // ---- phase K ----
    for (int i = t; i < 4096; i += 256) {
        int cc = i >> 6, j = i & 63;
        ws[i] = (j < 50) ? Wk[cc * 50 + j] : 0.f;
    }
    if (t < 64) bsh[t] = (t < 50) ? bk[t] : 0.f;
    __syncthreads();
    matvec16(xs, ws, bsh, r, sg, acc);
    {
        union { u16 s[16]; uint4 v[2]; } H, Lo;
        #pragma unroll
        for (int jj = 0; jj < 16; ++jj)
            bfsplit(fast_elu(acc[jj]), H.s[jj], Lo.s[jj]);
        const size_t off = ((size_t)b * L_ + l0 + r) * D_ + sg * 16;
        *(uint4*)(Khi + off) = H.v[0];  *(uint4*)(Khi + off + 8) = H.v[1];
        *(uint4*)(Klo + off) = Lo.v[0]; *(uint4*)(Klo + off + 8) = Lo.v[1];
    }
    __syncthreads();

    // ---- phase Q ----
    for (int i = t; i < 4096; i += 256) {
        int cc = i >> 6, j = i & 63;
        ws[i] = (j < 50) ? Wq[cc * 50 + j] : 0.f;
    }
    if (t < 64) bsh[t] = (t < 50) ? bq[t] : 0.f;
    __syncthreads();
    matvec16(xs, ws, bsh, r, sg, acc);
    {
        union { u16 s[16]; uint4 v[2]; } H, Lo;
        #pragma unroll
        for (int jj = 0; jj < 16; ++jj)
            bfsplit(fast_elu(acc[jj]) * sc2, H.s[jj], Lo.s[jj]);
        const size_t off = ((size_t)b * L_ + l0 + r) * D_ + sg * 16;
        *(uint4*)(Qhi + off) = H.v[0];  *(uint4*)(Qhi + off + 8) = H.v[1];
        *(uint4*)(Qlo + off) = Lo.v[0]; *(uint4*)(Qlo + off + 8) = Lo.v[1];
    }
    __syncthreads();

    // ---- phase V ----
    for (int i = t; i < 4096; i += 256) ws[i] = Wv[i];
    if (t < 64) bsh[t] = bv[t];
    __syncthreads();
    matvec16(xs, ws, bsh, r, sg, acc);
    #pragma unroll
    for (int jj = 0; jj < 16; ++jj)
        vt[(sg * 16 + jj) * 68 + r] = fast_tanh(acc[jj]);
    __syncthreads();
    {
        const int cB = t >> 2, ms = t & 3;
        const f32x4* vr = (const f32x4*)(vt + cB * 68 + ms * 16);
        union { u16 s[16]; uint4 v[2]; } H;
        #pragma unroll
        for (int q = 0; q < 4; ++q) {
            const f32x4 v4 = vr[q];
            #pragma unroll
            for (int i = 0; i < 4; ++i) H.s[q * 4 + i] = f2bf_rne(v4[i]);
        }
        const size_t off = ((size_t)b * 64 + cB) * L_ + l0 + ms * 16;
        *(uint4*)(Vthi + off) = H.v[0];  *(uint4*)(Vthi + off + 8) = H.v[1];
    }
}

// -------------------- Kernel 2: logZr[b][m] = -log2(sum_l 2^(k_l . q_m)) ----
// 32x32x16 MFMA version. Wave w: mt=w>>1 (m half), lt=w&1 (l half of chunk).
__global__ __launch_bounds__(256, 4)
void zsum_kernel(const u16* __restrict__ Khi, const u16* __restrict__ Klo,
                 const u16* __restrict__ Qhi, const u16* __restrict__ Qlo,
                 float* __restrict__ logZr)
{
    __shared__ __align__(16) u16 kh_s[64 * SR];
    __shared__ __align__(16) u16 kl_s[64 * SR];
    __shared__ float zpart[2][64];

    const int t = threadIdx.x;
    const int b = blockIdx.y;
    const int m0 = blockIdx.x * 64;
    const int wave = t >> 6, lane = t & 63;
    const int c31 = lane & 31, h = lane >> 5;
    const int mt = wave >> 1, lt = wave & 1;
    const int srow = t & 63, sseg = t >> 6;

    // Q fragments (A-operand), rows m = m0 + mt*32 + c31, in registers
    s16x8 qh[4], ql[4];
    {
        const size_t qb = ((size_t)b * L_ + m0 + mt * 32 + c31) * D_;
        #pragma unroll
        for (int ks = 0; ks < 4; ++ks) {
            qh[ks] = *(const s16x8*)(Qhi + qb + 8 * h + 16 * ks);
            ql[ks] = *(const s16x8*)(Qlo + qb + 8 * h + 16 * ks);
        }
    }

    float zacc[16];
    #pragma unroll
    for (int i = 0; i < 16; ++i) zacc[i] = 0.f;

    uint4 rk0, rk1, rk2, rk3;
    {
        const size_t kb = ((size_t)b * L_ + srow) * D_ + sseg * 16;
        rk0 = *(const uint4*)(Khi + kb); rk1 = *(const uint4*)(Khi + kb + 8);
        rk2 = *(const uint4*)(Klo + kb); rk3 = *(const uint4*)(Klo + kb + 8);
    }

    for (int ch = 0; ch < 32; ++ch) {
        __syncthreads();
        {
            const int lo = srow * SR + sseg * 16;
            *(uint4*)(kh_s + lo)     = rk0;  *(uint4*)(kh_s + lo + 8) = rk1;
            *(uint4*)(kl_s + lo)     = rk2;  *(uint4*)(kl_s + lo + 8) = rk3;
        }
        __syncthreads();
        if (ch < 31) {
            const size_t kb = ((size_t)b * L_ + (ch + 1) * 64 + srow) * D_ + sseg * 16;
            rk0 = *(const uint4*)(Khi + kb); rk1 = *(const uint4*)(Khi + kb + 8);
            rk2 = *(const uint4*)(Klo + kb); rk3 = *(const uint4*)(Klo + kb + 8);
        }
        f32x16 c1 = {}, c2 = {};   // independent hi / lo chains
        #pragma unroll
        for (int ks = 0; ks < 4; ++ks) {
            const int ko = (lt * 32 + c31) * SR + 8 * h + 16 * ks;
            const s16x8 bh = *(const s16x8*)(kh_s + ko);
            const s16x8 bl = *(const s16x8*)(kl_s + ko);
            c1 = mfma32(qh[ks], bh, c1);
            c1 = mfma32(qh[ks], bl, c1);
            c2 = mfma32(ql[ks], bh, c2);
        }
        #pragma unroll
        for (int i = 0; i < 16; ++i)
            zacc[i] += fexp2(fminf(c1[i] + c2[i], 80.f));
    }

    // reduce over the 32 l-columns (lane&31)
    #pragma unroll
    for (int off = 1; off < 32; off <<= 1)
        #pragma unroll
        for (int i = 0; i < 16; ++i)
            zacc[i] += __shfl_xor(zacc[i], off, 64);

    if (c31 == 0) {
        #pragma unroll
        for (int r = 0; r < 16; ++r)
            zpart[lt][mt * 32 + (r & 3) + 8 * (r >> 2) + 4 * h] = zacc[r];
    }
    __syncthreads();
    if (t < 64) {
        const float Z = zpart[0][t] + zpart[1][t];
        logZr[(size_t)b * L_ + m0 + t] = -log2f(fmaxf(Z, 1e-37f));
    }
}

// -------------------- Kernel 3: y[l][c] = sum_m 2^(s[m][l]-log2 Z[m]) v[m][c]
// 32x32x16 version. Wave w: mt=w>>1 (m half of chunk), lt=w&1 (l half).
// Each wave accumulates a PARTIAL y over its m half; pairs reduce at the end.
__global__ __launch_bounds__(256, 3)
void out_kernel(const u16* __restrict__ Khi, const u16* __restrict__ Klo,
                const u16* __restrict__ Qhi, const u16* __restrict__ Qlo,
                const u16* __restrict__ Vthi,
                const float* __restrict__ logZr,
                float* __restrict__ out)
{
    __shared__ __align__(16) union {
        struct { u16 qh[64 * SR]; u16 ql[64 * SR]; } kq;  // 16896 B
        float yred[64 * SR];                               // 16896 B (overlay)
    } ovl;
    __shared__ __align__(16) u16 vt_s[64 * SR];
    __shared__ __align__(16) u16 ph_s[4][32 * PR];         // per-wave P [l][m]
    __shared__ float zs_s[64];

    const int t = threadIdx.x;
    const int b = blockIdx.y;
    const int l0 = blockIdx.x * 64;
    const int wave = t >> 6, lane = t & 63;
    const int c31 = lane & 31, h = lane >> 5;
    const int mt = wave >> 1, lt = wave & 1;
    const int srow = t & 63, sseg = t >> 6;
    u16* const ph = ph_s[wave];

    // K fragments (B-operand of scores), rows l = l0 + lt*32 + c31, in regs
    s16x8 kh[4], kl[4];
    {
        const size_t kb = ((size_t)b * L_ + l0 + lt * 32 + c31) * D_;
        #pragma unroll
        for (int ks = 0; ks < 4; ++ks) {
            kh[ks] = *(const s16x8*)(Khi + kb + 8 * h + 16 * ks);
            kl[ks] = *(const s16x8*)(Klo + kb + 8 * h + 16 * ks);
        }
    }

    f32x16 acc0 = {}, acc1 = {};   // y partial, c-tiles 0 / 1

    uint4 rq0, rq1, rl0, rl1, rv0, rv1; float rz = 0.f;
    {
        const size_t qb = ((size_t)b * L_ + srow) * D_ + sseg * 16;
        const size_t vb = ((size_t)b * D_ + srow) * L_ + sseg * 16;
        rq0 = *(const uint4*)(Qhi + qb);  rq1 = *(const uint4*)(Qhi + qb + 8);
        rl0 = *(const uint4*)(Qlo + qb);  rl1 = *(const uint4*)(Qlo + qb + 8);
        rv0 = *(const uint4*)(Vthi + vb); rv1 = *(const uint4*)(Vthi + vb + 8);
        if (t < 64) rz = logZr[(size_t)b * L_ + t];
    }

    for (int ch = 0; ch < 32; ++ch) {
        __syncthreads();            // previous chunk's LDS reads done
        {
            const int lo = srow * SR + sseg * 16;
            *(uint4*)(ovl.kq.qh + lo)     = rq0; *(uint4*)(ovl.kq.qh + lo + 8) = rq1;
            *(uint4*)(ovl.kq.ql + lo)     = rl0; *(uint4*)(ovl.kq.ql + lo + 8) = rl1;
            *(uint4*)(vt_s + lo)          = rv0; *(uint4*)(vt_s + lo + 8)      = rv1;
            if (t < 64) zs_s[t] = rz;
        }
        __syncthreads();
        if (ch < 31) {
            const size_t qb = ((size_t)b * L_ + (ch + 1) * 64 + srow) * D_ + sseg * 16;
            const size_t vb = ((size_t)b * D_ + srow) * L_ + (ch + 1) * 64 + sseg * 16;
            rq0 = *(const uint4*)(Qhi + qb);  rq1 = *(const uint4*)(Qhi + qb + 8);
            rl0 = *(const uint4*)(Qlo + qb);  rl1 = *(const uint4*)(Qlo + qb + 8);
            rv0 = *(const uint4*)(Vthi + vb); rv1 = *(const uint4*)(Vthi + vb + 8);
            if (t < 64) rz = logZr[(size_t)b * L_ + (ch + 1) * 64 + t];
        }

        // ---- scores S[32m x 32l], C seeded with -log2 Z[m] ----
        f32x16 c1, c2 = {};
        #pragma unroll
        for (int q = 0; q < 4; ++q) {
            const f32x4 zq = *(const f32x4*)&zs_s[mt * 32 + 8 * q + 4 * h];
            #pragma unroll
            for (int i = 0; i < 4; ++i) c1[q * 4 + i] = zq[i];
        }
        #pragma unroll
        for (int ks = 0; ks < 4; ++ks) {
            const int ao = (mt * 32 + c31) * SR + 8 * h + 16 * ks;
            const s16x8 ah = *(const s16x8*)(ovl.kq.qh + ao);
            const s16x8 al = *(const s16x8*)(ovl.kq.ql + ao);
            c1 = mfma32(ah, kh[ks], c1);
            c1 = mfma32(ah, kl[ks], c1);
            c2 = mfma32(al, kh[ks], c2);
        }
        // P = 2^s (normalized), bf16, wave-private LDS in A-layout [l][m]
        #pragma unroll
        for (int q = 0; q < 4; ++q) {
            u16x4v p4;
            #pragma unroll
            for (int i = 0; i < 4; ++i)
                p4[i] = f2bf_rne(fexp2(fminf(c1[q * 4 + i] + c2[q * 4 + i], 80.f)));
            *(u16x4v*)(ph + c31 * PR + 8 * q + 4 * h) = p4;
        }
        // ---- PV: rank-32 update (this wave's m half) for both c-tiles ----
        #pragma unroll
        for (int ks = 0; ks < 2; ++ks) {
            const s16x8 pa = *(const s16x8*)(ph + c31 * PR + 8 * h + 16 * ks);
            const s16x8 bv0 = *(const s16x8*)(vt_s + c31 * SR        + mt * 32 + 8 * h + 16 * ks);
            const s16x8 bv1 = *(const s16x8*)(vt_s + (32 + c31) * SR + mt * 32 + 8 * h + 16 * ks);
            acc0 = mfma32(pa, bv0, acc0);
            acc1 = mfma32(pa, bv1, acc1);
        }
    }

    // ---- pairwise partial-y reduction (waves mt=1 -> LDS; mt=0 add+store) --
    __syncthreads();
    if (mt == 1) {
        #pragma unroll
        for (int r = 0; r < 16; ++r) {
            const int l = (r & 3) + 8 * (r >> 2) + 4 * h;
            ovl.yred[(lt * 32 + l) * SR + c31]      = acc0[r];
            ovl.yred[(lt * 32 + l) * SR + 32 + c31] = acc1[r];
        }
    }
    __syncthreads();
    if (mt == 0) {
        #pragma unroll
        for (int r = 0; r < 16; ++r) {
            const int l = (r & 3) + 8 * (r >> 2) + 4 * h;
            const size_t ob = ((size_t)b * L_ + l0 + lt * 32 + l) * D_;
            out[ob + c31]      = acc0[r] + ovl.yred[(lt * 32 + l) * SR + c31];
            out[ob + 32 + c31] = acc1[r] + ovl.yred[(lt * 32 + l) * SR + 32 + c31];
        }
    }
}

extern "C" void kernel_launch(void* const* d_in, const int* in_sizes, int n_in,
                              void* d_out, int out_size, void* d_ws, size_t ws_size,
                              hipStream_t stream)
{
    const float* x  = (const float*)d_in[0];
    const float* Wk = (const float*)d_in[1];
    const float* bk = (const float*)d_in[2];
    const float* Wq = (const float*)d_in[3];
    const float* bq = (const float*)d_in[4];
    const float* Wv = (const float*)d_in[5];
    const float* bv = (const float*)d_in[6];
    const int* slen = (const int*)d_in[7];
    float* out = (float*)d_out;

    const size_t n = (size_t)B_ * L_ * D_;
    float* logZr = (float*)d_ws;
    u16* Khi  = (u16*)(logZr + (size_t)B_ * L_);
    u16* Klo  = Khi + n;
    u16* Qhi  = Klo + n;
    u16* Qlo  = Qhi + n;
    u16* Vthi = Qlo + n;

    kqv_kernel<<<dim3(L_ / 64, B_), 256, 0, stream>>>(x, Wk, bk, Wq, bq, Wv, bv,
                                                      slen, Khi, Klo, Qhi, Qlo, Vthi);
    zsum_kernel<<<dim3(L_ / 64, B_), 256, 0, stream>>>(Khi, Klo, Qhi, Qlo, logZr);
    out_kernel<<<dim3(L_ / 64, B_), 256, 0, stream>>>(Khi, Klo, Qhi, Qlo, Vthi,
                                                      logZr, out);
}

// Round 7
// 261.028 us; speedup vs baseline: 1.3241x; 1.3241x over previous
//
#include <hip/hip_runtime.h>
#include <math.h>

#define B_  32
#define L_  2048
#define D_  64      // padded head dim (50 -> 64)
#define LOG2E 1.44269504088896340736f

typedef unsigned short u16;
typedef float f32x4 __attribute__((ext_vector_type(4)));
typedef short s16x8 __attribute__((ext_vector_type(8)));
typedef unsigned short u16x4v __attribute__((ext_vector_type(4)));

// 16B-block XOR swizzle within a 64-u16 (128B) row: rows stay 16B-aligned,
// column-fragment reads spread across all 8 bank groups.
__device__ inline int swz(int row, int blk) { return blk ^ (row & 7); }

__device__ inline float scalar_as_float(const int* p) {
    int v = *p;
    return (v > 0 && v < (1 << 23)) ? (float)v : __int_as_float(v);
}
__device__ inline float fexp2(float x) {
#if __has_builtin(__builtin_amdgcn_exp2f)
    return __builtin_amdgcn_exp2f(x);
#else
    return exp2f(x);
#endif
}
__device__ inline float frcp(float x) {
#if __has_builtin(__builtin_amdgcn_rcpf)
    return __builtin_amdgcn_rcpf(x);
#else
    return 1.0f / x;
#endif
}
__device__ inline float fast_elu(float a) {
    return a > 0.f ? a : fexp2(a * LOG2E) - 1.0f;
}
__device__ inline float fast_tanh(float a) {
    a = fminf(fmaxf(a, -20.f), 20.f);
    const float t = fexp2(a * (2.0f * LOG2E));
    return (t - 1.0f) * frcp(t + 1.0f);
}
__device__ inline u16 f2bf_rne(float f) {
    unsigned int u = __float_as_uint(f);
    u += 0x7fffu + ((u >> 16) & 1u);
    return (u16)(u >> 16);
}
__device__ inline void bfsplit(float x, u16& h, u16& l) {
    unsigned int u = __float_as_uint(x);
    h = (u16)(u >> 16);
    l = f2bf_rne(x - __uint_as_float(u & 0xffff0000u));
}
__device__ inline f32x4 mfma16(s16x8 a, s16x8 b, f32x4 c) {
    return __builtin_amdgcn_mfma_f32_16x16x32_bf16(a, b, c, 0, 0, 0);
}

// -------------------- Kernel 1: projections -> bf16 (round-5, unchanged) ---
__device__ inline void matvec16(const float (*xs)[64], const float* ws,
                                const float* bsh, int r, int sg, float* acc)
{
    #pragma unroll
    for (int jj = 0; jj < 16; ++jj) acc[jj] = bsh[sg * 16 + jj];
    #pragma unroll 4
    for (int c = 0; c < 64; ++c) {
        const float xv = xs[c][r];
        const f32x4* wr = (const f32x4*)(ws + c * 64 + sg * 16);
        #pragma unroll
        for (int q = 0; q < 4; ++q) {
            const f32x4 w = wr[q];
            #pragma unroll
            for (int i = 0; i < 4; ++i)
                acc[q * 4 + i] = fmaf(xv, w[i], acc[q * 4 + i]);
        }
    }
}

__global__ __launch_bounds__(256)
void kqv_kernel(const float* __restrict__ x,
                const float* __restrict__ Wk, const float* __restrict__ bk,
                const float* __restrict__ Wq, const float* __restrict__ bq,
                const float* __restrict__ Wv, const float* __restrict__ bv,
                const int* __restrict__ slen,
                u16* __restrict__ Khi, u16* __restrict__ Klo,
                u16* __restrict__ Qhi, u16* __restrict__ Qlo,
                u16* __restrict__ Vthi)
{
    __shared__ __align__(16) float xs[64][64];
    __shared__ __align__(16) float ws[64 * 64];
    __shared__ __align__(16) float vt[64 * 68];
    __shared__ __align__(16) float bsh[64];

    const int t  = threadIdx.x;
    const int b  = blockIdx.y;
    const int l0 = blockIdx.x * 64;
    const int li = t & 63;
    const int g  = t >> 6;
    const int r  = t >> 2;
    const int sg = t & 3;

    for (int c = g; c < 64; c += 4)
        xs[c][li] = x[((size_t)b * 64 + c) * L_ + l0 + li];

    const float sc2 = rsqrtf(scalar_as_float(slen)) * LOG2E;
    float acc[16];

    // ---- phase K ----
    for (int i = t; i < 4096; i += 256) {
        int cc = i >> 6, j = i & 63;
        ws[i] = (j < 50) ? Wk[cc * 50 + j] : 0.f;
    }
    if (t < 64) bsh[t] = (t < 50) ? bk[t] : 0.f;
    __syncthreads();
    matvec16(xs, ws, bsh, r, sg, acc);
    {
        union { u16 s[16]; uint4 v[2]; } H, Lo;
        #pragma unroll
        for (int jj = 0; jj < 16; ++jj)
            bfsplit(fast_elu(acc[jj]), H.s[jj], Lo.s[jj]);
        const size_t off = ((size_t)b * L_ + l0 + r) * D_ + sg * 16;
        *(uint4*)(Khi + off) = H.v[0];  *(uint4*)(Khi + off + 8) = H.v[1];
        *(uint4*)(Klo + off) = Lo.v[0]; *(uint4*)(Klo + off + 8) = Lo.v[1];
    }
    __syncthreads();

    // ---- phase Q ----
    for (int i = t; i < 4096; i += 256) {
        int cc = i >> 6, j = i & 63;
        ws[i] = (j < 50) ? Wq[cc * 50 + j] : 0.f;
    }
    if (t < 64) bsh[t] = (t < 50) ? bq[t] : 0.f;
    __syncthreads();
    matvec16(xs, ws, bsh, r, sg, acc);
    {
        union { u16 s[16]; uint4 v[2]; } H, Lo;
        #pragma unroll
        for (int jj = 0; jj < 16; ++jj)
            bfsplit(fast_elu(acc[jj]) * sc2, H.s[jj], Lo.s[jj]);
        const size_t off = ((size_t)b * L_ + l0 + r) * D_ + sg * 16;
        *(uint4*)(Qhi + off) = H.v[0];  *(uint4*)(Qhi + off + 8) = H.v[1];
        *(uint4*)(Qlo + off) = Lo.v[0]; *(uint4*)(Qlo + off + 8) = Lo.v[1];
    }
    __syncthreads();

    // ---- phase V ----
    for (int i = t; i < 4096; i += 256) ws[i] = Wv[i];
    if (t < 64) bsh[t] = bv[t];
    __syncthreads();
    matvec16(xs, ws, bsh, r, sg, acc);
    #pragma unroll
    for (int jj = 0; jj < 16; ++jj)
        vt[(sg * 16 + jj) * 68 + r] = fast_tanh(acc[jj]);
    __syncthreads();
    {
        const int cB = t >> 2, ms = t & 3;
        const f32x4* vr = (const f32x4*)(vt + cB * 68 + ms * 16);
        union { u16 s[16]; uint4 v[2]; } H;
        #pragma unroll
        for (int q = 0; q < 4; ++q) {
            const f32x4 v4 = vr[q];
            #pragma unroll
            for (int i = 0; i < 4; ++i) H.s[q * 4 + i] = f2bf_rne(v4[i]);
        }
        const size_t off = ((size_t)b * 64 + cB) * L_ + l0 + ms * 16;
        *(uint4*)(Vthi + off) = H.v[0];  *(uint4*)(Vthi + off + 8) = H.v[1];
    }
}

// -------- Kernel 2: Z[b,m] = sum_l 2^(k_l.q_m); then V[:,m] *= 1/Z[m] ------
__global__ __launch_bounds__(256, 4)
void zsum_kernel(const u16* __restrict__ Khi, const u16* __restrict__ Klo,
                 const u16* __restrict__ Qhi, const u16* __restrict__ Qlo,
                 u16* __restrict__ Vthi)
{
    __shared__ __align__(16) u16 kh_s[64 * 64];
    __shared__ __align__(16) u16 kl_s[64 * 64];
    __shared__ float zs[64];

    const int t = threadIdx.x;
    const int b = blockIdx.y;
    const int m0 = blockIdx.x * 64;
    const int wave = t >> 6;
    const int lane = t & 63;
    const int l15 = lane & 15;
    const int quad = lane >> 4;
    const int r = t >> 2, sg = t & 3;

    // A-operand (Q) rows m = m0 + wave*16 + l15, in registers
    const size_t qrow = ((size_t)b * L_ + m0 + wave * 16 + l15) * D_;
    const s16x8 qh0 = *(const s16x8*)(Qhi + qrow + quad * 8);
    const s16x8 qh1 = *(const s16x8*)(Qhi + qrow + 32 + quad * 8);
    const s16x8 ql0 = *(const s16x8*)(Qlo + qrow + quad * 8);
    const s16x8 ql1 = *(const s16x8*)(Qlo + qrow + 32 + quad * 8);

    float zacc[4] = {0.f, 0.f, 0.f, 0.f};

    uint4 rk0, rk1, rk2, rk3;
    {
        const size_t kb = ((size_t)b * L_ + r) * D_ + sg * 16;
        rk0 = *(const uint4*)(Khi + kb); rk1 = *(const uint4*)(Khi + kb + 8);
        rk2 = *(const uint4*)(Klo + kb); rk3 = *(const uint4*)(Klo + kb + 8);
    }

    const int lo0 = r * 64 + (swz(r, 2 * sg) << 3);
    const int lo1 = r * 64 + (swz(r, 2 * sg + 1) << 3);

    for (int ch = 0; ch < 32; ++ch) {
        __syncthreads();
        *(uint4*)(kh_s + lo0) = rk0;  *(uint4*)(kh_s + lo1) = rk1;
        *(uint4*)(kl_s + lo0) = rk2;  *(uint4*)(kl_s + lo1) = rk3;
        __syncthreads();
        if (ch < 31) {
            const size_t kb = ((size_t)b * L_ + (ch + 1) * 64 + r) * D_ + sg * 16;
            rk0 = *(const uint4*)(Khi + kb); rk1 = *(const uint4*)(Khi + kb + 8);
            rk2 = *(const uint4*)(Klo + kb); rk3 = *(const uint4*)(Klo + kb + 8);
        }
        #pragma unroll
        for (int lt = 0; lt < 4; ++lt) {
            const int row = lt * 16 + l15;
            const int o0 = row * 64 + (swz(row, quad) << 3);
            const int o1 = row * 64 + (swz(row, quad | 4) << 3);
            const s16x8 bh0 = *(const s16x8*)(kh_s + o0);
            const s16x8 bh1 = *(const s16x8*)(kh_s + o1);
            const s16x8 bl0 = *(const s16x8*)(kl_s + o0);
            const s16x8 bl1 = *(const s16x8*)(kl_s + o1);
            f32x4 s = {0.f, 0.f, 0.f, 0.f};
            s = mfma16(qh0, bh0, s);
            s = mfma16(qh1, bh1, s);
            s = mfma16(qh0, bl0, s);
            s = mfma16(qh1, bl1, s);
            s = mfma16(ql0, bh0, s);
            s = mfma16(ql1, bh1, s);
            #pragma unroll
            for (int i = 0; i < 4; ++i) zacc[i] += fexp2(fminf(s[i], 80.f));
        }
    }

    // reduce over the 16 l-columns (lanes sharing quad)
    #pragma unroll
    for (int off = 1; off < 16; off <<= 1)
        #pragma unroll
        for (int i = 0; i < 4; ++i)
            zacc[i] += __shfl_xor(zacc[i], off, 64);

    if (l15 == 0) {
        #pragma unroll
        for (int i = 0; i < 4; ++i)
            zs[wave * 16 + quad * 4 + i] = frcp(fmaxf(zacc[i], 1e-30f));
    }
    __syncthreads();

    // ---- normalize this block's V columns in place: V[:, m] *= 1/Z[m] ----
    {
        const size_t vb = ((size_t)b * 64 + r) * L_ + m0 + sg * 16;
        union { u16 s[16]; uint4 v[2]; } V;
        V.v[0] = *(const uint4*)(Vthi + vb);
        V.v[1] = *(const uint4*)(Vthi + vb + 8);
        #pragma unroll
        for (int i = 0; i < 16; ++i) {
            const float f = __uint_as_float((unsigned int)V.s[i] << 16) * zs[sg * 16 + i];
            V.s[i] = f2bf_rne(f);
        }
        *(uint4*)(Vthi + vb)     = V.v[0];
        *(uint4*)(Vthi + vb + 8) = V.v[1];
    }
}

// -------- Kernel 3: y[l,c] = sum_m 2^(k_l.q_m) * Vn[m,c]  (V pre-normalized)
__global__ __launch_bounds__(256, 4)
void out_kernel(const u16* __restrict__ Khi, const u16* __restrict__ Klo,
                const u16* __restrict__ Qhi, const u16* __restrict__ Qlo,
                const u16* __restrict__ Vthi,
                float* __restrict__ out)
{
    __shared__ __align__(16) u16 qh_s[64 * 64], ql_s[64 * 64];
    __shared__ __align__(16) u16 vn_s[64 * 64];
    __shared__ __align__(16) u16 ph_s[4][16 * 64];   // per-wave P' [l][m]

    const int t = threadIdx.x;
    const int b = blockIdx.y;
    const int l0 = blockIdx.x * 64;
    const int wave = t >> 6;
    const int lane = t & 63;
    const int l15 = lane & 15;
    const int quad = lane >> 4;
    const int r = t >> 2, sg = t & 3;
    u16* const ph = ph_s[wave];

    // K fragments (B-operand of scores): rows l = l0 + wave*16 + l15, in regs
    const size_t krow = ((size_t)b * L_ + l0 + wave * 16 + l15) * D_;
    const s16x8 kh0 = *(const s16x8*)(Khi + krow + quad * 8);
    const s16x8 kh1 = *(const s16x8*)(Khi + krow + 32 + quad * 8);
    const s16x8 kl0 = *(const s16x8*)(Klo + krow + quad * 8);
    const s16x8 kl1 = *(const s16x8*)(Klo + krow + 32 + quad * 8);

    f32x4 acc[4];
    #pragma unroll
    for (int ct = 0; ct < 4; ++ct) acc[ct] = (f32x4){0.f, 0.f, 0.f, 0.f};

    uint4 rq0, rq1, rl0, rl1, rv0, rv1;
    {
        const size_t qb = ((size_t)b * L_ + r) * D_ + sg * 16;
        const size_t vb = ((size_t)b * 64 + r) * L_ + sg * 16;
        rq0 = *(const uint4*)(Qhi + qb);  rq1 = *(const uint4*)(Qhi + qb + 8);
        rl0 = *(const uint4*)(Qlo + qb);  rl1 = *(const uint4*)(Qlo + qb + 8);
        rv0 = *(const uint4*)(Vthi + vb); rv1 = *(const uint4*)(Vthi + vb + 8);
    }

    const int lo0 = r * 64 + (swz(r, 2 * sg) << 3);
    const int lo1 = r * 64 + (swz(r, 2 * sg + 1) << 3);

    for (int ch = 0; ch < 32; ++ch) {
        __syncthreads();            // previous chunk's LDS reads done
        *(uint4*)(qh_s + lo0) = rq0; *(uint4*)(qh_s + lo1) = rq1;
        *(uint4*)(ql_s + lo0) = rl0; *(uint4*)(ql_s + lo1) = rl1;
        *(uint4*)(vn_s + lo0) = rv0; *(uint4*)(vn_s + lo1) = rv1;
        __syncthreads();
        if (ch < 31) {
            const size_t qb = ((size_t)b * L_ + (ch + 1) * 64 + r) * D_ + sg * 16;
            const size_t vb = ((size_t)b * 64 + r) * L_ + (ch + 1) * 64 + sg * 16;
            rq0 = *(const uint4*)(Qhi + qb);  rq1 = *(const uint4*)(Qhi + qb + 8);
            rl0 = *(const uint4*)(Qlo + qb);  rl1 = *(const uint4*)(Qlo + qb + 8);
            rv0 = *(const uint4*)(Vthi + vb); rv1 = *(const uint4*)(Vthi + vb + 8);
        }

        // scores S[m][l] for 4 m-tiles; P' = 2^S (unnormalized; V carries 1/Z)
        #pragma unroll
        for (int mt = 0; mt < 4; ++mt) {
            const int row = mt * 16 + l15;
            const int o0 = row * 64 + (swz(row, quad) << 3);
            const int o1 = row * 64 + (swz(row, quad | 4) << 3);
            const s16x8 ah0 = *(const s16x8*)(qh_s + o0);
            const s16x8 ah1 = *(const s16x8*)(qh_s + o1);
            const s16x8 al0 = *(const s16x8*)(ql_s + o0);
            const s16x8 al1 = *(const s16x8*)(ql_s + o1);
            f32x4 s = {0.f, 0.f, 0.f, 0.f};
            s = mfma16(ah0, kh0, s);
            s = mfma16(ah1, kh1, s);
            s = mfma16(ah0, kl0, s);
            s = mfma16(ah1, kl1, s);
            s = mfma16(al0, kh0, s);
            s = mfma16(al1, kh1, s);
            u16x4v p4;
            #pragma unroll
            for (int i = 0; i < 4; ++i)
                p4[i] = f2bf_rne(fexp2(fminf(s[i], 80.f)));
            // C-layout -> A-layout [l][m], swizzled half-block write (8B)
            const int pw = l15 * 64 + (swz(l15, 2 * mt + (quad >> 1)) << 3) + (quad & 1) * 4;
            *(u16x4v*)(ph + pw) = p4;
        }
        // ph is wave-private; per-wave DS ordering suffices (no barrier)

        // PV: rank-64 update of the wave's 16l x 64c tile
        #pragma unroll
        for (int ks = 0; ks < 2; ++ks) {
            const s16x8 pa = *(const s16x8*)(ph + l15 * 64 + (swz(l15, 4 * ks + quad) << 3));
            #pragma unroll
            for (int ct = 0; ct < 4; ++ct) {
                const int vrow = ct * 16 + l15;
                const s16x8 bvh = *(const s16x8*)(vn_s + vrow * 64 + (swz(vrow, 4 * ks + quad) << 3));
                acc[ct] = mfma16(pa, bvh, acc[ct]);
            }
        }
    }

    const int row = l0 + wave * 16 + quad * 4;
    #pragma unroll
    for (int ct = 0; ct < 4; ++ct)
        #pragma unroll
        for (int i = 0; i < 4; ++i)
            out[((size_t)b * L_ + row + i) * 64 + ct * 16 + l15] = acc[ct][i];
}

extern "C" void kernel_launch(void* const* d_in, const int* in_sizes, int n_in,
                              void* d_out, int out_size, void* d_ws, size_t ws_size,
                              hipStream_t stream)
{
    const float* x  = (const float*)d_in[0];
    const float* Wk = (const float*)d_in[1];
    const float* bk = (const float*)d_in[2];
    const float* Wq = (const float*)d_in[3];
    const float* bq = (const float*)d_in[4];
    const float* Wv = (const float*)d_in[5];
    const float* bv = (const float*)d_in[6];
    const int* slen = (const int*)d_in[7];
    float* out = (float*)d_out;

    const size_t n = (size_t)B_ * L_ * D_;
    u16* Khi  = (u16*)d_ws;
    u16* Klo  = Khi + n;
    u16* Qhi  = Klo + n;
    u16* Qlo  = Qhi + n;
    u16* Vthi = Qlo + n;

    kqv_kernel<<<dim3(L_ / 64, B_), 256, 0, stream>>>(x, Wk, bk, Wq, bq, Wv, bv,
                                                      slen, Khi, Klo, Qhi, Qlo, Vthi);
    zsum_kernel<<<dim3(L_ / 64, B_), 256, 0, stream>>>(Khi, Klo, Qhi, Qlo, Vthi);
    out_kernel<<<dim3(L_ / 64, B_), 256, 0, stream>>>(Khi, Klo, Qhi, Qlo, Vthi, out);
}

// Round 8
// 247.843 us; speedup vs baseline: 1.3945x; 1.0532x over previous
//
#include <hip/hip_runtime.h>
#include <math.h>

#define B_  32
#define L_  2048
#define D_  64      // padded head dim (50 -> 64)
#define LOG2E 1.44269504088896340736f

typedef unsigned short u16;
typedef float f32x4 __attribute__((ext_vector_type(4)));
typedef short s16x8 __attribute__((ext_vector_type(8)));
typedef unsigned short u16x4v __attribute__((ext_vector_type(4)));

// 16B-block XOR swizzle within a 64-u16 (128B) row: rows stay 16B-aligned,
// column-fragment reads spread across all 8 bank groups.
__device__ inline int swz(int row, int blk) { return blk ^ (row & 7); }

__device__ inline float scalar_as_float(const int* p) {
    int v = *p;
    return (v > 0 && v < (1 << 23)) ? (float)v : __int_as_float(v);
}
__device__ inline float fexp2(float x) {
#if __has_builtin(__builtin_amdgcn_exp2f)
    return __builtin_amdgcn_exp2f(x);
#else
    return exp2f(x);
#endif
}
__device__ inline float frcp(float x) {
#if __has_builtin(__builtin_amdgcn_rcpf)
    return __builtin_amdgcn_rcpf(x);
#else
    return 1.0f / x;
#endif
}
__device__ inline float fast_elu(float a) {
    return a > 0.f ? a : fexp2(a * LOG2E) - 1.0f;
}
__device__ inline float fast_tanh(float a) {
    a = fminf(fmaxf(a, -20.f), 20.f);
    const float t = fexp2(a * (2.0f * LOG2E));
    return (t - 1.0f) * frcp(t + 1.0f);
}
__device__ inline u16 f2bf_rne(float f) {
    unsigned int u = __float_as_uint(f);
    u += 0x7fffu + ((u >> 16) & 1u);
    return (u16)(u >> 16);
}
__device__ inline void bfsplit(float x, u16& h, u16& l) {
    unsigned int u = __float_as_uint(x);
    h = (u16)(u >> 16);
    l = f2bf_rne(x - __uint_as_float(u & 0xffff0000u));
}
__device__ inline f32x4 mfma16(s16x8 a, s16x8 b, f32x4 c) {
    return __builtin_amdgcn_mfma_f32_16x16x32_bf16(a, b, c, 0, 0, 0);
}

// -------------------- Kernel 1: projections via MFMA -----------------------
// C[l][ch] = sum_c xT[l][c] * W[c][ch] + bias[ch]; A = xT (split bf16),
// B = W^T rows=ch (split bf16), 3-term MFMA, elu/tanh epilogue.
__global__ __launch_bounds__(256)
void kqv_kernel(const float* __restrict__ x,
                const float* __restrict__ Wk, const float* __restrict__ bk,
                const float* __restrict__ Wq, const float* __restrict__ bq,
                const float* __restrict__ Wv, const float* __restrict__ bv,
                const int* __restrict__ slen,
                u16* __restrict__ Khi, u16* __restrict__ Klo,
                u16* __restrict__ Qhi, u16* __restrict__ Qlo,
                u16* __restrict__ Vthi)
{
    __shared__ __align__(16) float xs[64 * 65];            // xT fp32, stride 65
    __shared__ __align__(16) u16 ah[64 * 64], al[64 * 64]; // xT split, swizzled
    __shared__ __align__(16) u16 wh[64 * 64], wl[64 * 64]; // W^T split, swizzled
    __shared__ float bsh[192];

    const int t = threadIdx.x;
    const int b = blockIdx.y;
    const int l0 = blockIdx.x * 64;
    const int wave = t >> 6;
    const int lane = t & 63;
    const int l15 = lane & 15;
    const int quad = lane >> 4;

    // ---- stage x -> xs transposed [l][c] (fp32; bank-conflict-free) ----
    #pragma unroll
    for (int it = 0; it < 4; ++it) {
        const int c = (t >> 4) + it * 16;
        const int l4 = (t & 15) * 4;
        const float4 v = *(const float4*)&x[((size_t)b * 64 + c) * L_ + l0 + l4];
        xs[(l4 + 0) * 65 + c] = v.x;
        xs[(l4 + 1) * 65 + c] = v.y;
        xs[(l4 + 2) * 65 + c] = v.z;
        xs[(l4 + 3) * 65 + c] = v.w;
    }
    if (t < 64)       bsh[t] = (t < 50) ? bk[t] : 0.f;
    else if (t < 128) bsh[t] = (t - 64 < 50) ? bq[t - 64] : 0.f;
    else if (t < 192) bsh[t] = bv[t - 128];
    __syncthreads();

    // ---- convert xs -> split-bf16 A-operand (swizzled rows) ----
    {
        const int l = t >> 2, sg = t & 3;
        union { u16 s[8]; uint4 v; } H0, H1, L0, L1;
        #pragma unroll
        for (int j = 0; j < 8; ++j) {
            bfsplit(xs[l * 65 + sg * 16 + j],     H0.s[j], L0.s[j]);
            bfsplit(xs[l * 65 + sg * 16 + 8 + j], H1.s[j], L1.s[j]);
        }
        *(uint4*)(ah + l * 64 + (swz(l, 2 * sg) << 3))     = H0.v;
        *(uint4*)(ah + l * 64 + (swz(l, 2 * sg + 1) << 3)) = H1.v;
        *(uint4*)(al + l * 64 + (swz(l, 2 * sg) << 3))     = L0.v;
        *(uint4*)(al + l * 64 + (swz(l, 2 * sg + 1) << 3)) = L1.v;
    }
    __syncthreads();

    // ---- A fragments, rows l = wave*16 + l15 (persist across phases) ----
    const int arow = wave * 16 + l15;
    const s16x8 ah0 = *(const s16x8*)(ah + arow * 64 + (swz(arow, quad) << 3));
    const s16x8 ah1 = *(const s16x8*)(ah + arow * 64 + (swz(arow, quad | 4) << 3));
    const s16x8 al0 = *(const s16x8*)(al + arow * 64 + (swz(arow, quad) << 3));
    const s16x8 al1 = *(const s16x8*)(al + arow * 64 + (swz(arow, quad | 4) << 3));

    const float sc2 = rsqrtf(scalar_as_float(slen)) * LOG2E;

    for (int ph = 0; ph < 3; ++ph) {
        __syncthreads();   // previous phase done reading wh/wl
        {
            const int ch = t & 63, c0 = wave * 16;
            const float* W = (ph == 0) ? Wk : (ph == 1) ? Wq : Wv;
            const int wd = (ph == 2) ? 64 : 50;
            #pragma unroll 4
            for (int j = 0; j < 16; ++j) {
                const int c = c0 + j;
                const float wv_ = (ch < wd) ? W[c * wd + ch] : 0.f;
                u16 h, lo; bfsplit(wv_, h, lo);
                const int idx = ch * 64 + (swz(ch, c >> 3) << 3) + (c & 7);
                wh[idx] = h; wl[idx] = lo;
            }
        }
        __syncthreads();

        #pragma unroll
        for (int ct = 0; ct < 4; ++ct) {
            const int brow = ct * 16 + l15;
            const s16x8 bh0 = *(const s16x8*)(wh + brow * 64 + (swz(brow, quad) << 3));
            const s16x8 bh1 = *(const s16x8*)(wh + brow * 64 + (swz(brow, quad | 4) << 3));
            const s16x8 bl0 = *(const s16x8*)(wl + brow * 64 + (swz(brow, quad) << 3));
            const s16x8 bl1 = *(const s16x8*)(wl + brow * 64 + (swz(brow, quad | 4) << 3));
            const float bb = bsh[ph * 64 + brow];
            f32x4 c = {bb, bb, bb, bb};
            c = mfma16(ah0, bh0, c);
            c = mfma16(ah1, bh1, c);
            c = mfma16(ah0, bl0, c);
            c = mfma16(ah1, bl1, c);
            c = mfma16(al0, bh0, c);
            c = mfma16(al1, bh1, c);

            if (ph < 2) {
                u16* __restrict__ Hi = (ph == 0) ? Khi : Qhi;
                u16* __restrict__ Lo = (ph == 0) ? Klo : Qlo;
                #pragma unroll
                for (int i = 0; i < 4; ++i) {
                    float a = fast_elu(c[i]);
                    if (ph == 1) a *= sc2;
                    u16 h, lo; bfsplit(a, h, lo);
                    const size_t off = ((size_t)b * L_ + l0 + wave * 16 + quad * 4 + i) * D_ + brow;
                    Hi[off] = h; Lo[off] = lo;
                }
            } else {
                u16x4v p;
                #pragma unroll
                for (int i = 0; i < 4; ++i) p[i] = f2bf_rne(fast_tanh(c[i]));
                const size_t off = ((size_t)b * 64 + brow) * L_ + l0 + wave * 16 + quad * 4;
                *(u16x4v*)(Vthi + off) = p;   // 4 consecutive l -> 8B store
            }
        }
    }
}

// -------- Kernel 2: Z[b,m] = sum_l 2^(k_l.q_m); then V[:,m] *= 1/Z[m] ------
__global__ __launch_bounds__(256, 4)
void zsum_kernel(const u16* __restrict__ Khi, const u16* __restrict__ Klo,
                 const u16* __restrict__ Qhi, const u16* __restrict__ Qlo,
                 u16* __restrict__ Vthi)
{
    __shared__ __align__(16) u16 kh_s[64 * 64];
    __shared__ __align__(16) u16 kl_s[64 * 64];
    __shared__ float zs[64];

    const int t = threadIdx.x;
    const int b = blockIdx.y;
    const int m0 = blockIdx.x * 64;
    const int wave = t >> 6;
    const int lane = t & 63;
    const int l15 = lane & 15;
    const int quad = lane >> 4;
    const int r = t >> 2, sg = t & 3;

    // A-operand (Q) rows m = m0 + wave*16 + l15, in registers
    const size_t qrow = ((size_t)b * L_ + m0 + wave * 16 + l15) * D_;
    const s16x8 qh0 = *(const s16x8*)(Qhi + qrow + quad * 8);
    const s16x8 qh1 = *(const s16x8*)(Qhi + qrow + 32 + quad * 8);
    const s16x8 ql0 = *(const s16x8*)(Qlo + qrow + quad * 8);
    const s16x8 ql1 = *(const s16x8*)(Qlo + qrow + 32 + quad * 8);

    float zacc[4] = {0.f, 0.f, 0.f, 0.f};

    uint4 rk0, rk1, rk2, rk3;
    {
        const size_t kb = ((size_t)b * L_ + r) * D_ + sg * 16;
        rk0 = *(const uint4*)(Khi + kb); rk1 = *(const uint4*)(Khi + kb + 8);
        rk2 = *(const uint4*)(Klo + kb); rk3 = *(const uint4*)(Klo + kb + 8);
    }

    const int lo0 = r * 64 + (swz(r, 2 * sg) << 3);
    const int lo1 = r * 64 + (swz(r, 2 * sg + 1) << 3);

    for (int ch = 0; ch < 32; ++ch) {
        __syncthreads();
        *(uint4*)(kh_s + lo0) = rk0;  *(uint4*)(kh_s + lo1) = rk1;
        *(uint4*)(kl_s + lo0) = rk2;  *(uint4*)(kl_s + lo1) = rk3;
        __syncthreads();
        if (ch < 31) {
            const size_t kb = ((size_t)b * L_ + (ch + 1) * 64 + r) * D_ + sg * 16;
            rk0 = *(const uint4*)(Khi + kb); rk1 = *(const uint4*)(Khi + kb + 8);
            rk2 = *(const uint4*)(Klo + kb); rk3 = *(const uint4*)(Klo + kb + 8);
        }
        #pragma unroll
        for (int lt = 0; lt < 4; ++lt) {
            const int row = lt * 16 + l15;
            const int o0 = row * 64 + (swz(row, quad) << 3);
            const int o1 = row * 64 + (swz(row, quad | 4) << 3);
            const s16x8 bh0 = *(const s16x8*)(kh_s + o0);
            const s16x8 bh1 = *(const s16x8*)(kh_s + o1);
            const s16x8 bl0 = *(const s16x8*)(kl_s + o0);
            const s16x8 bl1 = *(const s16x8*)(kl_s + o1);
            f32x4 s = {0.f, 0.f, 0.f, 0.f};
            s = mfma16(qh0, bh0, s);
            s = mfma16(qh1, bh1, s);
            s = mfma16(qh0, bl0, s);
            s = mfma16(qh1, bl1, s);
            s = mfma16(ql0, bh0, s);
            s = mfma16(ql1, bh1, s);
            #pragma unroll
            for (int i = 0; i < 4; ++i) zacc[i] += fexp2(fminf(s[i], 80.f));
        }
    }

    #pragma unroll
    for (int off = 1; off < 16; off <<= 1)
        #pragma unroll
        for (int i = 0; i < 4; ++i)
            zacc[i] += __shfl_xor(zacc[i], off, 64);

    if (l15 == 0) {
        #pragma unroll
        for (int i = 0; i < 4; ++i)
            zs[wave * 16 + quad * 4 + i] = frcp(fmaxf(zacc[i], 1e-30f));
    }
    __syncthreads();

    // normalize this block's V columns in place: V[:, m] *= 1/Z[m]
    {
        const size_t vb = ((size_t)b * 64 + r) * L_ + m0 + sg * 16;
        union { u16 s[16]; uint4 v[2]; } V;
        V.v[0] = *(const uint4*)(Vthi + vb);
        V.v[1] = *(const uint4*)(Vthi + vb + 8);
        #pragma unroll
        for (int i = 0; i < 16; ++i) {
            const float f = __uint_as_float((unsigned int)V.s[i] << 16) * zs[sg * 16 + i];
            V.s[i] = f2bf_rne(f);
        }
        *(uint4*)(Vthi + vb)     = V.v[0];
        *(uint4*)(Vthi + vb + 8) = V.v[1];
    }
}

// -------- Kernel 3: y[l,c] = sum_m 2^(k_l.q_m) * Vn[m,c]  (V pre-normalized)
__global__ __launch_bounds__(256, 4)
void out_kernel(const u16* __restrict__ Khi, const u16* __restrict__ Klo,
                const u16* __restrict__ Qhi, const u16* __restrict__ Qlo,
                const u16* __restrict__ Vthi,
                float* __restrict__ out)
{
    __shared__ __align__(16) u16 qh_s[64 * 64], ql_s[64 * 64];
    __shared__ __align__(16) u16 vn_s[64 * 64];
    __shared__ __align__(16) u16 ph_s[4][16 * 64];   // per-wave P' [l][m]

    const int t = threadIdx.x;
    const int b = blockIdx.y;
    const int l0 = blockIdx.x * 64;
    const int wave = t >> 6;
    const int lane = t & 63;
    const int l15 = lane & 15;
    const int quad = lane >> 4;
    const int r = t >> 2, sg = t & 3;
    u16* const ph = ph_s[wave];

    const size_t krow = ((size_t)b * L_ + l0 + wave * 16 + l15) * D_;
    const s16x8 kh0 = *(const s16x8*)(Khi + krow + quad * 8);
    const s16x8 kh1 = *(const s16x8*)(Khi + krow + 32 + quad * 8);
    const s16x8 kl0 = *(const s16x8*)(Klo + krow + quad * 8);
    const s16x8 kl1 = *(const s16x8*)(Klo + krow + 32 + quad * 8);

    f32x4 acc[4];
    #pragma unroll
    for (int ct = 0; ct < 4; ++ct) acc[ct] = (f32x4){0.f, 0.f, 0.f, 0.f};

    uint4 rq0, rq1, rl0, rl1, rv0, rv1;
    {
        const size_t qb = ((size_t)b * L_ + r) * D_ + sg * 16;
        const size_t vb = ((size_t)b * 64 + r) * L_ + sg * 16;
        rq0 = *(const uint4*)(Qhi + qb);  rq1 = *(const uint4*)(Qhi + qb + 8);
        rl0 = *(const uint4*)(Qlo + qb);  rl1 = *(const uint4*)(Qlo + qb + 8);
        rv0 = *(const uint4*)(Vthi + vb); rv1 = *(const uint4*)(Vthi + vb + 8);
    }

    const int lo0 = r * 64 + (swz(r, 2 * sg) << 3);
    const int lo1 = r * 64 + (swz(r, 2 * sg + 1) << 3);

    for (int ch = 0; ch < 32; ++ch) {
        __syncthreads();
        *(uint4*)(qh_s + lo0) = rq0; *(uint4*)(qh_s + lo1) = rq1;
        *(uint4*)(ql_s + lo0) = rl0; *(uint4*)(ql_s + lo1) = rl1;
        *(uint4*)(vn_s + lo0) = rv0; *(uint4*)(vn_s + lo1) = rv1;
        __syncthreads();
        if (ch < 31) {
            const size_t qb = ((size_t)b * L_ + (ch + 1) * 64 + r) * D_ + sg * 16;
            const size_t vb = ((size_t)b * 64 + r) * L_ + (ch + 1) * 64 + sg * 16;
            rq0 = *(const uint4*)(Qhi + qb);  rq1 = *(const uint4*)(Qhi + qb + 8);
            rl0 = *(const uint4*)(Qlo + qb);  rl1 = *(const uint4*)(Qlo + qb + 8);
            rv0 = *(const uint4*)(Vthi + vb); rv1 = *(const uint4*)(Vthi + vb + 8);
        }

        #pragma unroll
        for (int mt = 0; mt < 4; ++mt) {
            const int row = mt * 16 + l15;
            const int o0 = row * 64 + (swz(row, quad) << 3);
            const int o1 = row * 64 + (swz(row, quad | 4) << 3);
            const s16x8 ah0 = *(const s16x8*)(qh_s + o0);
            const s16x8 ah1 = *(const s16x8*)(qh_s + o1);
            const s16x8 al0 = *(const s16x8*)(ql_s + o0);
            const s16x8 al1 = *(const s16x8*)(ql_s + o1);
            f32x4 s = {0.f, 0.f, 0.f, 0.f};
            s = mfma16(ah0, kh0, s);
            s = mfma16(ah1, kh1, s);
            s = mfma16(ah0, kl0, s);
            s = mfma16(ah1, kl1, s);
            s = mfma16(al0, kh0, s);
            s = mfma16(al1, kh1, s);
            u16x4v p4;
            #pragma unroll
            for (int i = 0; i < 4; ++i)
                p4[i] = f2bf_rne(fexp2(fminf(s[i], 80.f)));
            const int pw = l15 * 64 + (swz(l15, 2 * mt + (quad >> 1)) << 3) + (quad & 1) * 4;
            *(u16x4v*)(ph + pw) = p4;
        }

        #pragma unroll
        for (int ks = 0; ks < 2; ++ks) {
            const s16x8 pa = *(const s16x8*)(ph + l15 * 64 + (swz(l15, 4 * ks + quad) << 3));
            #pragma unroll
            for (int ct = 0; ct < 4; ++ct) {
                const int vrow = ct * 16 + l15;
                const s16x8 bvh = *(const s16x8*)(vn_s + vrow * 64 + (swz(vrow, 4 * ks + quad) << 3));
                acc[ct] = mfma16(pa, bvh, acc[ct]);
            }
        }
    }

    const int row = l0 + wave * 16 + quad * 4;
    #pragma unroll
    for (int ct = 0; ct < 4; ++ct)
        #pragma unroll
        for (int i = 0; i < 4; ++i)
            out[((size_t)b * L_ + row + i) * 64 + ct * 16 + l15] = acc[ct][i];
}

extern "C" void kernel_launch(void* const* d_in, const int* in_sizes, int n_in,
                              void* d_out, int out_size, void* d_ws, size_t ws_size,
                              hipStream_t stream)
{
    const float* x  = (const float*)d_in[0];
    const float* Wk = (const float*)d_in[1];
    const float* bk = (const float*)d_in[2];
    const float* Wq = (const float*)d_in[3];
    const float* bq = (const float*)d_in[4];
    const float* Wv = (const float*)d_in[5];
    const float* bv = (const float*)d_in[6];
    const int* slen = (const int*)d_in[7];
    float* out = (float*)d_out;

    const size_t n = (size_t)B_ * L_ * D_;
    u16* Khi  = (u16*)d_ws;
    u16* Klo  = Khi + n;
    u16* Qhi  = Klo + n;
    u16* Qlo  = Qhi + n;
    u16* Vthi = Qlo + n;

    kqv_kernel<<<dim3(L_ / 64, B_), 256, 0, stream>>>(x, Wk, bk, Wq, bq, Wv, bv,
                                                      slen, Khi, Klo, Qhi, Qlo, Vthi);
    zsum_kernel<<<dim3(L_ / 64, B_), 256, 0, stream>>>(Khi, Klo, Qhi, Qlo, Vthi);
    out_kernel<<<dim3(L_ / 64, B_), 256, 0, stream>>>(Khi, Klo, Qhi, Qlo, Vthi, out);
}

// Round 9
// 228.973 us; speedup vs baseline: 1.5095x; 1.0824x over previous
//
#include <hip/hip_runtime.h>
#include <math.h>

#define B_  32
#define L_  2048
#define D_  64      // padded head dim (50 -> 64)
#define LOG2E 1.44269504088896340736f

typedef unsigned short u16;
typedef float f32x4 __attribute__((ext_vector_type(4)));
typedef short s16x8 __attribute__((ext_vector_type(8)));
typedef unsigned short u16x4v __attribute__((ext_vector_type(4)));

// 16B-block XOR swizzle within a 64-u16 (128B) row: rows stay 16B-aligned,
// column-fragment reads spread across all 8 bank groups.
__device__ inline int swz(int row, int blk) { return blk ^ (row & 7); }

__device__ inline float scalar_as_float(const int* p) {
    int v = *p;
    return (v > 0 && v < (1 << 23)) ? (float)v : __int_as_float(v);
}
__device__ inline float fexp2(float x) {
#if __has_builtin(__builtin_amdgcn_exp2f)
    return __builtin_amdgcn_exp2f(x);
#else
    return exp2f(x);
#endif
}
__device__ inline float frcp(float x) {
#if __has_builtin(__builtin_amdgcn_rcpf)
    return __builtin_amdgcn_rcpf(x);
#else
    return 1.0f / x;
#endif
}
__device__ inline float fast_elu(float a) {
    return a > 0.f ? a : fexp2(a * LOG2E) - 1.0f;
}
__device__ inline float fast_tanh(float a) {
    a = fminf(fmaxf(a, -20.f), 20.f);
    const float t = fexp2(a * (2.0f * LOG2E));
    return (t - 1.0f) * frcp(t + 1.0f);
}
__device__ inline u16 f2bf_rne(float f) {
    unsigned int u = __float_as_uint(f);
    u += 0x7fffu + ((u >> 16) & 1u);
    return (u16)(u >> 16);
}
__device__ inline void bfsplit(float x, u16& h, u16& l) {
    unsigned int u = __float_as_uint(x);
    h = (u16)(u >> 16);
    l = f2bf_rne(x - __uint_as_float(u & 0xffff0000u));
}
__device__ inline f32x4 mfma16(s16x8 a, s16x8 b, f32x4 c) {
    return __builtin_amdgcn_mfma_f32_16x16x32_bf16(a, b, c, 0, 0, 0);
}

// -------------------- Kernel 1: projections via MFMA -----------------------
// K bf16-RNE only (perturbed-K scheme); Q split hi/lo; V transposed bf16.
__global__ __launch_bounds__(256)
void kqv_kernel(const float* __restrict__ x,
                const float* __restrict__ Wk, const float* __restrict__ bk,
                const float* __restrict__ Wq, const float* __restrict__ bq,
                const float* __restrict__ Wv, const float* __restrict__ bv,
                const int* __restrict__ slen,
                u16* __restrict__ Khi,
                u16* __restrict__ Qhi, u16* __restrict__ Qlo,
                u16* __restrict__ Vthi)
{
    __shared__ __align__(16) float xs[64 * 65];            // xT fp32, stride 65
    __shared__ __align__(16) u16 ah[64 * 64], al[64 * 64]; // xT split, swizzled
    __shared__ __align__(16) u16 wh[64 * 64], wl[64 * 64]; // W^T split, swizzled
    __shared__ float bsh[192];

    const int t = threadIdx.x;
    const int b = blockIdx.y;
    const int l0 = blockIdx.x * 64;
    const int wave = t >> 6;
    const int lane = t & 63;
    const int l15 = lane & 15;
    const int quad = lane >> 4;

    // ---- stage x -> xs transposed [l][c] (fp32; 2-way alias only) ----
    #pragma unroll
    for (int it = 0; it < 4; ++it) {
        const int c = (t >> 4) + it * 16;
        const int l4 = (t & 15) * 4;
        const float4 v = *(const float4*)&x[((size_t)b * 64 + c) * L_ + l0 + l4];
        xs[(l4 + 0) * 65 + c] = v.x;
        xs[(l4 + 1) * 65 + c] = v.y;
        xs[(l4 + 2) * 65 + c] = v.z;
        xs[(l4 + 3) * 65 + c] = v.w;
    }
    if (t < 64)       bsh[t] = (t < 50) ? bk[t] : 0.f;
    else if (t < 128) bsh[t] = (t - 64 < 50) ? bq[t - 64] : 0.f;
    else if (t < 192) bsh[t] = bv[t - 128];
    __syncthreads();

    // ---- convert xs -> split-bf16 A-operand (swizzled rows) ----
    {
        const int l = t >> 2, sg = t & 3;
        union { u16 s[8]; uint4 v; } H0, H1, L0, L1;
        #pragma unroll
        for (int j = 0; j < 8; ++j) {
            bfsplit(xs[l * 65 + sg * 16 + j],     H0.s[j], L0.s[j]);
            bfsplit(xs[l * 65 + sg * 16 + 8 + j], H1.s[j], L1.s[j]);
        }
        *(uint4*)(ah + l * 64 + (swz(l, 2 * sg) << 3))     = H0.v;
        *(uint4*)(ah + l * 64 + (swz(l, 2 * sg + 1) << 3)) = H1.v;
        *(uint4*)(al + l * 64 + (swz(l, 2 * sg) << 3))     = L0.v;
        *(uint4*)(al + l * 64 + (swz(l, 2 * sg + 1) << 3)) = L1.v;
    }
    __syncthreads();

    // ---- A fragments, rows l = wave*16 + l15 (persist across phases) ----
    const int arow = wave * 16 + l15;
    const s16x8 ah0 = *(const s16x8*)(ah + arow * 64 + (swz(arow, quad) << 3));
    const s16x8 ah1 = *(const s16x8*)(ah + arow * 64 + (swz(arow, quad | 4) << 3));
    const s16x8 al0 = *(const s16x8*)(al + arow * 64 + (swz(arow, quad) << 3));
    const s16x8 al1 = *(const s16x8*)(al + arow * 64 + (swz(arow, quad | 4) << 3));

    const float sc2 = rsqrtf(scalar_as_float(slen)) * LOG2E;

    for (int ph = 0; ph < 3; ++ph) {
        __syncthreads();   // previous phase done reading wh/wl
        {
            const int ch = t & 63, c0 = wave * 16;
            const float* W = (ph == 0) ? Wk : (ph == 1) ? Wq : Wv;
            const int wd = (ph == 2) ? 64 : 50;
            #pragma unroll 4
            for (int j = 0; j < 16; ++j) {
                const int c = c0 + j;
                const float wv_ = (ch < wd) ? W[c * wd + ch] : 0.f;
                u16 h, lo; bfsplit(wv_, h, lo);
                const int idx = ch * 64 + (swz(ch, c >> 3) << 3) + (c & 7);
                wh[idx] = h; wl[idx] = lo;
            }
        }
        __syncthreads();

        #pragma unroll
        for (int ct = 0; ct < 4; ++ct) {
            const int brow = ct * 16 + l15;
            const s16x8 bh0 = *(const s16x8*)(wh + brow * 64 + (swz(brow, quad) << 3));
            const s16x8 bh1 = *(const s16x8*)(wh + brow * 64 + (swz(brow, quad | 4) << 3));
            const s16x8 bl0 = *(const s16x8*)(wl + brow * 64 + (swz(brow, quad) << 3));
            const s16x8 bl1 = *(const s16x8*)(wl + brow * 64 + (swz(brow, quad | 4) << 3));
            const float bb = bsh[ph * 64 + brow];
            f32x4 c = {bb, bb, bb, bb};
            c = mfma16(ah0, bh0, c);
            c = mfma16(ah1, bh1, c);
            c = mfma16(ah0, bl0, c);
            c = mfma16(ah1, bl1, c);
            c = mfma16(al0, bh0, c);
            c = mfma16(al1, bh1, c);

            if (ph == 0) {
                #pragma unroll
                for (int i = 0; i < 4; ++i) {
                    const size_t off = ((size_t)b * L_ + l0 + wave * 16 + quad * 4 + i) * D_ + brow;
                    Khi[off] = f2bf_rne(fast_elu(c[i]));   // K: plain bf16 (RNE)
                }
            } else if (ph == 1) {
                #pragma unroll
                for (int i = 0; i < 4; ++i) {
                    float a = fast_elu(c[i]) * sc2;
                    u16 h, lo; bfsplit(a, h, lo);
                    const size_t off = ((size_t)b * L_ + l0 + wave * 16 + quad * 4 + i) * D_ + brow;
                    Qhi[off] = h; Qlo[off] = lo;
                }
            } else {
                u16x4v p;
                #pragma unroll
                for (int i = 0; i < 4; ++i) p[i] = f2bf_rne(fast_tanh(c[i]));
                const size_t off = ((size_t)b * 64 + brow) * L_ + l0 + wave * 16 + quad * 4;
                *(u16x4v*)(Vthi + off) = p;   // 4 consecutive l -> 8B store
            }
        }
    }
}

// -------- Kernel 2: Z[b,m] = sum_l 2^(q_m.k_l); then V[:,m] *= 1/Z[m] ------
__global__ __launch_bounds__(256, 4)
void zsum_kernel(const u16* __restrict__ Khi,
                 const u16* __restrict__ Qhi, const u16* __restrict__ Qlo,
                 u16* __restrict__ Vthi)
{
    __shared__ __align__(16) u16 kh_s[64 * 64];
    __shared__ float zs[64];

    const int t = threadIdx.x;
    const int b = blockIdx.y;
    const int m0 = blockIdx.x * 64;
    const int wave = t >> 6;
    const int lane = t & 63;
    const int l15 = lane & 15;
    const int quad = lane >> 4;
    const int r = t >> 2, sg = t & 3;

    // A-operand (Q, split) rows m = m0 + wave*16 + l15, in registers
    const size_t qrow = ((size_t)b * L_ + m0 + wave * 16 + l15) * D_;
    const s16x8 qh0 = *(const s16x8*)(Qhi + qrow + quad * 8);
    const s16x8 qh1 = *(const s16x8*)(Qhi + qrow + 32 + quad * 8);
    const s16x8 ql0 = *(const s16x8*)(Qlo + qrow + quad * 8);
    const s16x8 ql1 = *(const s16x8*)(Qlo + qrow + 32 + quad * 8);

    float zacc[4] = {0.f, 0.f, 0.f, 0.f};

    uint4 rk0, rk1;
    {
        const size_t kb = ((size_t)b * L_ + r) * D_ + sg * 16;
        rk0 = *(const uint4*)(Khi + kb); rk1 = *(const uint4*)(Khi + kb + 8);
    }

    const int lo0 = r * 64 + (swz(r, 2 * sg) << 3);
    const int lo1 = r * 64 + (swz(r, 2 * sg + 1) << 3);

    for (int ch = 0; ch < 32; ++ch) {
        __syncthreads();
        *(uint4*)(kh_s + lo0) = rk0;  *(uint4*)(kh_s + lo1) = rk1;
        __syncthreads();
        if (ch < 31) {
            const size_t kb = ((size_t)b * L_ + (ch + 1) * 64 + r) * D_ + sg * 16;
            rk0 = *(const uint4*)(Khi + kb); rk1 = *(const uint4*)(Khi + kb + 8);
        }
        #pragma unroll
        for (int lt = 0; lt < 4; ++lt) {
            const int row = lt * 16 + l15;
            const int o0 = row * 64 + (swz(row, quad) << 3);
            const int o1 = row * 64 + (swz(row, quad | 4) << 3);
            const s16x8 bh0 = *(const s16x8*)(kh_s + o0);
            const s16x8 bh1 = *(const s16x8*)(kh_s + o1);
            f32x4 s1 = {0.f, 0.f, 0.f, 0.f};   // q_hi . k
            f32x4 s2 = {0.f, 0.f, 0.f, 0.f};   // q_lo . k (independent chain)
            s1 = mfma16(qh0, bh0, s1);
            s1 = mfma16(qh1, bh1, s1);
            s2 = mfma16(ql0, bh0, s2);
            s2 = mfma16(ql1, bh1, s2);
            #pragma unroll
            for (int i = 0; i < 4; ++i)
                zacc[i] += fexp2(fminf(s1[i] + s2[i], 80.f));
        }
    }

    #pragma unroll
    for (int off = 1; off < 16; off <<= 1)
        #pragma unroll
        for (int i = 0; i < 4; ++i)
            zacc[i] += __shfl_xor(zacc[i], off, 64);

    if (l15 == 0) {
        #pragma unroll
        for (int i = 0; i < 4; ++i)
            zs[wave * 16 + quad * 4 + i] = frcp(fmaxf(zacc[i], 1e-30f));
    }
    __syncthreads();

    // normalize this block's V columns in place: V[:, m] *= 1/Z[m]
    {
        const size_t vb = ((size_t)b * 64 + r) * L_ + m0 + sg * 16;
        union { u16 s[16]; uint4 v[2]; } V;
        V.v[0] = *(const uint4*)(Vthi + vb);
        V.v[1] = *(const uint4*)(Vthi + vb + 8);
        #pragma unroll
        for (int i = 0; i < 16; ++i) {
            const float f = __uint_as_float((unsigned int)V.s[i] << 16) * zs[sg * 16 + i];
            V.s[i] = f2bf_rne(f);
        }
        *(uint4*)(Vthi + vb)     = V.v[0];
        *(uint4*)(Vthi + vb + 8) = V.v[1];
    }
}

// -------- Kernel 3: y[l,c] = sum_m 2^(q_m.k_l) * Vn[m,c]  (V pre-normalized)
__global__ __launch_bounds__(256, 4)
void out_kernel(const u16* __restrict__ Khi,
                const u16* __restrict__ Qhi, const u16* __restrict__ Qlo,
                const u16* __restrict__ Vthi,
                float* __restrict__ out)
{
    __shared__ __align__(16) u16 qh_s[64 * 64], ql_s[64 * 64];
    __shared__ __align__(16) u16 vn_s[64 * 64];
    __shared__ __align__(16) u16 ph_s[4][16 * 64];   // per-wave P' [l][m]

    const int t = threadIdx.x;
    const int b = blockIdx.y;
    const int l0 = blockIdx.x * 64;
    const int wave = t >> 6;
    const int lane = t & 63;
    const int l15 = lane & 15;
    const int quad = lane >> 4;
    const int r = t >> 2, sg = t & 3;
    u16* const ph = ph_s[wave];

    // K fragments (bf16 only): rows l = l0 + wave*16 + l15, in regs
    const size_t krow = ((size_t)b * L_ + l0 + wave * 16 + l15) * D_;
    const s16x8 kh0 = *(const s16x8*)(Khi + krow + quad * 8);
    const s16x8 kh1 = *(const s16x8*)(Khi + krow + 32 + quad * 8);

    f32x4 acc[4];
    #pragma unroll
    for (int ct = 0; ct < 4; ++ct) acc[ct] = (f32x4){0.f, 0.f, 0.f, 0.f};

    uint4 rq0, rq1, rl0, rl1, rv0, rv1;
    {
        const size_t qb = ((size_t)b * L_ + r) * D_ + sg * 16;
        const size_t vb = ((size_t)b * 64 + r) * L_ + sg * 16;
        rq0 = *(const uint4*)(Qhi + qb);  rq1 = *(const uint4*)(Qhi + qb + 8);
        rl0 = *(const uint4*)(Qlo + qb);  rl1 = *(const uint4*)(Qlo + qb + 8);
        rv0 = *(const uint4*)(Vthi + vb); rv1 = *(const uint4*)(Vthi + vb + 8);
    }

    const int lo0 = r * 64 + (swz(r, 2 * sg) << 3);
    const int lo1 = r * 64 + (swz(r, 2 * sg + 1) << 3);

    for (int ch = 0; ch < 32; ++ch) {
        __syncthreads();
        *(uint4*)(qh_s + lo0) = rq0; *(uint4*)(qh_s + lo1) = rq1;
        *(uint4*)(ql_s + lo0) = rl0; *(uint4*)(ql_s + lo1) = rl1;
        *(uint4*)(vn_s + lo0) = rv0; *(uint4*)(vn_s + lo1) = rv1;
        __syncthreads();
        if (ch < 31) {
            const size_t qb = ((size_t)b * L_ + (ch + 1) * 64 + r) * D_ + sg * 16;
            const size_t vb = ((size_t)b * 64 + r) * L_ + (ch + 1) * 64 + sg * 16;
            rq0 = *(const uint4*)(Qhi + qb);  rq1 = *(const uint4*)(Qhi + qb + 8);
            rl0 = *(const uint4*)(Qlo + qb);  rl1 = *(const uint4*)(Qlo + qb + 8);
            rv0 = *(const uint4*)(Vthi + vb); rv1 = *(const uint4*)(Vthi + vb + 8);
        }

        // scores S[m][l] for 4 m-tiles; P' = 2^S (unnormalized; V carries 1/Z)
        #pragma unroll
        for (int mt = 0; mt < 4; ++mt) {
            const int row = mt * 16 + l15;
            const int o0 = row * 64 + (swz(row, quad) << 3);
            const int o1 = row * 64 + (swz(row, quad | 4) << 3);
            const s16x8 ah0 = *(const s16x8*)(qh_s + o0);
            const s16x8 ah1 = *(const s16x8*)(qh_s + o1);
            const s16x8 al0 = *(const s16x8*)(ql_s + o0);
            const s16x8 al1 = *(const s16x8*)(ql_s + o1);
            f32x4 s1 = {0.f, 0.f, 0.f, 0.f};
            f32x4 s2 = {0.f, 0.f, 0.f, 0.f};
            s1 = mfma16(ah0, kh0, s1);
            s1 = mfma16(ah1, kh1, s1);
            s2 = mfma16(al0, kh0, s2);
            s2 = mfma16(al1, kh1, s2);
            u16x4v p4;
            #pragma unroll
            for (int i = 0; i < 4; ++i)
                p4[i] = f2bf_rne(fexp2(fminf(s1[i] + s2[i], 80.f)));
            const int pw = l15 * 64 + (swz(l15, 2 * mt + (quad >> 1)) << 3) + (quad & 1) * 4;
            *(u16x4v*)(ph + pw) = p4;
        }

        // PV: rank-64 update of the wave's 16l x 64c tile
        #pragma unroll
        for (int ks = 0; ks < 2; ++ks) {
            const s16x8 pa = *(const s16x8*)(ph + l15 * 64 + (swz(l15, 4 * ks + quad) << 3));
            #pragma unroll
            for (int ct = 0; ct < 4; ++ct) {
                const int vrow = ct * 16 + l15;
                const s16x8 bvh = *(const s16x8*)(vn_s + vrow * 64 + (swz(vrow, 4 * ks + quad) << 3));
                acc[ct] = mfma16(pa, bvh, acc[ct]);
            }
        }
    }

    const int row = l0 + wave * 16 + quad * 4;
    #pragma unroll
    for (int ct = 0; ct < 4; ++ct)
        #pragma unroll
        for (int i = 0; i < 4; ++i)
            out[((size_t)b * L_ + row + i) * 64 + ct * 16 + l15] = acc[ct][i];
}

extern "C" void kernel_launch(void* const* d_in, const int* in_sizes, int n_in,
                              void* d_out, int out_size, void* d_ws, size_t ws_size,
                              hipStream_t stream)
{
    const float* x  = (const float*)d_in[0];
    const float* Wk = (const float*)d_in[1];
    const float* bk = (const float*)d_in[2];
    const float* Wq = (const float*)d_in[3];
    const float* bq = (const float*)d_in[4];
    const float* Wv = (const float*)d_in[5];
    const float* bv = (const float*)d_in[6];
    const int* slen = (const int*)d_in[7];
    float* out = (float*)d_out;

    const size_t n = (size_t)B_ * L_ * D_;   // 4 arrays x 8 MB = 32 MB
    u16* Khi  = (u16*)d_ws;
    u16* Qhi  = Khi + n;
    u16* Qlo  = Qhi + n;
    u16* Vthi = Qlo + n;

    kqv_kernel<<<dim3(L_ / 64, B_), 256, 0, stream>>>(x, Wk, bk, Wq, bq, Wv, bv,
                                                      slen, Khi, Qhi, Qlo, Vthi);
    zsum_kernel<<<dim3(L_ / 64, B_), 256, 0, stream>>>(Khi, Qhi, Qlo, Vthi);
    out_kernel<<<dim3(L_ / 64, B_), 256, 0, stream>>>(Khi, Qhi, Qlo, Vthi, out);
}